// Round 20
// baseline (94.260 us; speedup 1.0000x reference)
//
#include <hip/hip_runtime.h>
#include <hip/hip_bf16.h>
#include <math.h>

#define B_ 32
#define T_ 128
#define C_ 64
#define E_ 8
#define HID_ 32

#define LOG2E 1.44269504088896341f

__device__ __forceinline__ float fast_rcp(float x) { return __builtin_amdgcn_rcpf(x); }
__device__ __forceinline__ float fast_exp2(float x) { return exp2f(x); }
__device__ __forceinline__ float fast_sigmoid(float x) {
    return fast_rcp(1.0f + fast_exp2(-LOG2E * x));
}
__device__ __forceinline__ float fast_tanh(float x) {
    float xc = __builtin_amdgcn_fmed3f(x, -15.0f, 15.0f);
    float t = fast_exp2(2.0f * LOG2E * xc);
    return (t - 1.0f) * fast_rcp(t + 1.0f);
}

template <int CTRL>
__device__ __forceinline__ float dppf(float v) {
    return __int_as_float(__builtin_amdgcn_update_dpp(
        __float_as_int(v), __float_as_int(v), CTRL, 0xF, 0xF, false));
}
#define QP_XOR1 0xB1
#define QP_XOR2 0x4E
#define QP_XOR3 0x1B
#define HALF_MIRROR 0x141

// ---------------------------------------------------------------------------
// K0: xp row + ts_imp for one (b,t). grid = B*T, block = 64. (proven)
// ---------------------------------------------------------------------------
__global__ __launch_bounds__(64) void k_pre_ts(
    const float* __restrict__ x, const float* __restrict__ W_in, const float* __restrict__ b_in,
    const float* __restrict__ W_ts1, const float* __restrict__ b_ts1,
    const float* __restrict__ W_ts2, const float* __restrict__ b_ts2,
    float* __restrict__ xp, float* __restrict__ ts_imp)
{
    const int bt = blockIdx.x;
    const int tid = threadIdx.x;
    __shared__ __align__(16) float xs[C_];
    __shared__ float h1[16];
    if (tid < 16) ((float4*)xs)[tid] = ((const float4*)(x + bt * C_))[tid];
    __syncthreads();

    float a = b_in[tid];
    const float4* w4 = (const float4*)(W_in + tid * C_);
#pragma unroll
    for (int k4 = 0; k4 < 16; ++k4) {
        float4 xv = ((const float4*)xs)[k4];
        float4 wv = w4[k4];
        a = fmaf(xv.x, wv.x, a); a = fmaf(xv.y, wv.y, a);
        a = fmaf(xv.z, wv.z, a); a = fmaf(xv.w, wv.w, a);
    }
    xp[bt * C_ + tid] = a;

    if (tid < 16) {
        float s = b_ts1[tid];
#pragma unroll
        for (int k = 0; k < C_; ++k) s = fmaf(xs[k], W_ts1[tid * C_ + k], s);
        h1[tid] = 0.5f * s * (1.0f + erff(s * 0.70710678118654752f));
    }
    __syncthreads();
    if (tid == 0) {
        float s = b_ts2[0];
#pragma unroll
        for (int k = 0; k < 16; ++k) s = fmaf(h1[k], W_ts2[k], s);
        ts_imp[bt] = fast_sigmoid(s);
    }
}

// ---------------------------------------------------------------------------
// K1: GRU (r18, unchanged).
// ---------------------------------------------------------------------------
__global__ __launch_bounds__(64) void k_gru(
    const float* __restrict__ xp, const float* __restrict__ W_ih, const float* __restrict__ W_hh,
    const float* __restrict__ b_ih, const float* __restrict__ b_hh,
    float* __restrict__ hs, float* __restrict__ fh)
{
    const int tid = threadIdx.x;
    const int ci = tid >> 3;
    const int e = tid & 7;
    const int chain = blockIdx.x * 8 + ci;
    const int c = chain & 63;

    __shared__ float xc[8][T_ + 1];

    const int c_base = (blockIdx.x & 7) * 8;
    const int bb = blockIdx.x >> 3;
    for (int idx = tid; idx < 8 * T_; idx += 64) {
        int cci = idx & 7, t = idx >> 3;
        xc[cci][t] = xp[(bb * T_ + t) * C_ + c_base + cci];
    }
    __syncthreads();

    float wr[8], wz[8], wn[8];
#pragma unroll
    for (int m = 0; m < 8; ++m) {
        const int j = e ^ m;
        wr[m] = W_hh[(c * 24 + 0  + e) * 8 + j];
        wz[m] = W_hh[(c * 24 + 8  + e) * 8 + j];
        wn[m] = W_hh[(c * 24 + 16 + e) * 8 + j];
    }
    const float wir = W_ih[c * 24 + e], wiz = W_ih[c * 24 + 8 + e], win = W_ih[c * 24 + 16 + e];
    const float cr = b_ih[c * 24 + e] + b_hh[c * 24 + e];
    const float cz = b_ih[c * 24 + 8 + e] + b_hh[c * 24 + 8 + e];
    const float bin_ = b_ih[c * 24 + 16 + e];
    const float bhn  = b_hh[c * 24 + 16 + e];

    float h = 0.0f;
    float* ho = hs + (size_t)chain * T_ * E_ + e;
    float xv = xc[ci][0];
    for (int t = 0; t < T_; ++t) {
        float xvn = xc[ci][t + 1];
        float p1 = dppf<QP_XOR1>(h);
        float p2 = dppf<QP_XOR2>(h);
        float p3 = dppf<QP_XOR3>(h);
        float p7 = dppf<HALF_MIRROR>(h);
        float p6 = dppf<HALF_MIRROR>(p1);
        float p5 = dppf<HALF_MIRROR>(p2);
        float p4 = dppf<HALF_MIRROR>(p3);
        const float pa[8] = {h, p1, p2, p3, p4, p5, p6, p7};

        float g0 = fmaf(pa[1], wr[1], pa[0] * wr[0]);
        float g1 = fmaf(pa[3], wr[3], pa[2] * wr[2]);
        float g2 = fmaf(pa[5], wr[5], pa[4] * wr[4]);
        float g3 = fmaf(pa[7], wr[7], pa[6] * wr[6]);
        float gr = fmaf(xv, wir, cr) + ((g0 + g1) + (g2 + g3));
        float z0 = fmaf(pa[1], wz[1], pa[0] * wz[0]);
        float z1 = fmaf(pa[3], wz[3], pa[2] * wz[2]);
        float z2 = fmaf(pa[5], wz[5], pa[4] * wz[4]);
        float z3 = fmaf(pa[7], wz[7], pa[6] * wz[6]);
        float gz = fmaf(xv, wiz, cz) + ((z0 + z1) + (z2 + z3));
        float n0 = fmaf(pa[1], wn[1], pa[0] * wn[0]);
        float n1 = fmaf(pa[3], wn[3], pa[2] * wn[2]);
        float n2 = fmaf(pa[5], wn[5], pa[4] * wn[4]);
        float n3 = fmaf(pa[7], wn[7], pa[6] * wn[6]);
        float hn = bhn + ((n0 + n1) + (n2 + n3));
        float gn = fmaf(xv, win, bin_);
        float r = fast_sigmoid(gr);
        float z = fast_sigmoid(gz);
        float nn = fast_tanh(fmaf(r, hn, gn));
        h = fmaf(z, h - nn, nn);
        ho[t * E_] = h;
        xv = xvn;
    }
    fh[chain * E_ + e] = h;
}

// ---------------------------------------------------------------------------
// K2: attention. grid = B*C, block = 128 = 2 waves.
// Wave w owns rows [64w, 64w+64). lane = 2*ri+sh: rows {64w+ri, 64w+32+ri},
// s in [64*sh, 64*sh+64). ks/us halves padded +4 floats so the sh=1 half is
// bank-shifted by 4 -> every wave LDS read touches 8 distinct banks.
// Partner combine via shfl_xor(1); 2 barriers total; LDS ~10.1 KB.
// ---------------------------------------------------------------------------
__global__ __launch_bounds__(128) void k_attn(
    const float* __restrict__ hs, const float* __restrict__ W_qkv, const float* __restrict__ b_qkv,
    const float* __restrict__ W_o, const float* __restrict__ b_o,
    float* __restrict__ feat_imp, float* __restrict__ tsf_imp)
{
    const int bc = blockIdx.x;
    const int b = bc >> 6, c = bc & 63;
    const int tid = threadIdx.x;
    const int w = tid >> 6;
    const int lane = tid & 63;
    const int ri = lane >> 1;
    const int sh = lane & 1;
    const int row0 = w * 64 + ri;
    const int row1 = w * 64 + 32 + ri;

    __shared__ __align__(16) float ks[2][516];   // 64*8 + 4 pad per half
    __shared__ __align__(16) float us[2][260];   // 64*4 + 4 pad per half
    __shared__ float qsT[E_][T_];                // 4 KB
    __shared__ float red2[2];

    const float qscale = 0.70710678118654752f * LOG2E;

    // staging: thread handles q, k, u of row tid
    {
        const int srow = tid;
        const float4* hp = (const float4*)(hs + (size_t)bc * T_ * E_ + srow * E_);
        float4 h0 = hp[0], h1 = hp[1];
        float hr[E_] = {h0.x, h0.y, h0.z, h0.w, h1.x, h1.y, h1.z, h1.w};
        float* kdst = &ks[srow >> 6][(srow & 63) * 8];
        float kv[E_];
#pragma unroll
        for (int f = 0; f < E_; ++f) {
            float a = b_qkv[E_ + f];
#pragma unroll
            for (int j = 0; j < E_; ++j) a = fmaf(hr[j], W_qkv[(E_ + f) * E_ + j], a);
            kv[f] = a;
        }
        ((float4*)kdst)[0] = make_float4(kv[0], kv[1], kv[2], kv[3]);
        ((float4*)kdst)[1] = make_float4(kv[4], kv[5], kv[6], kv[7]);
#pragma unroll
        for (int f = 0; f < E_; ++f) {
            float a = b_qkv[f];
#pragma unroll
            for (int j = 0; j < E_; ++j) a = fmaf(hr[j], W_qkv[f * E_ + j], a);
            qsT[f][srow] = a * qscale;
        }
        float ws[E_];
#pragma unroll
        for (int d = 0; d < E_; ++d) {               // uniform -> scalar loads
            float wv = 0.0f;
#pragma unroll
            for (int fp = 0; fp < E_; ++fp) wv += W_o[fp * E_ + d];
            ws[d] = wv;
        }
        float vv[E_];
#pragma unroll
        for (int f = 0; f < E_; ++f) {
            float a = b_qkv[2 * E_ + f];
#pragma unroll
            for (int j = 0; j < E_; ++j) a = fmaf(hr[j], W_qkv[(2 * E_ + f) * E_ + j], a);
            vv[f] = a;
        }
        float4 uu;
        uu.x = fmaf(vv[1], ws[1], vv[0] * ws[0]);
        uu.y = fmaf(vv[3], ws[3], vv[2] * ws[2]);
        uu.z = fmaf(vv[5], ws[5], vv[4] * ws[4]);
        uu.w = fmaf(vv[7], ws[7], vv[6] * ws[6]);
        *((float4*)&us[srow >> 6][(srow & 63) * 4]) = uu;
    }
    __syncthreads();

    // q for this lane's two rows (qsT banks = row%32; pairs broadcast -> free)
    float q0[E_], q1[E_];
#pragma unroll
    for (int f = 0; f < E_; ++f) { q0[f] = qsT[f][row0]; q1[f] = qsT[f][row1]; }

    // main loop: 64 s-values of this lane's half; k/u reads serve 2 rows
    float l0[4] = {0.f,0.f,0.f,0.f}, S0[4] = {0.f,0.f,0.f,0.f};
    float l1[4] = {0.f,0.f,0.f,0.f}, S1[4] = {0.f,0.f,0.f,0.f};
    const float* kb = &ks[sh][0];
    const float* ub = &us[sh][0];
#pragma unroll 8
    for (int i = 0; i < 64; ++i) {
        float4 k0 = *(const float4*)(kb + i * 8);
        float4 k1 = *(const float4*)(kb + i * 8 + 4);
        float4 uu = *(const float4*)(ub + i * 4);
        float p00 = fast_exp2(fmaf(q0[1], k0.y, q0[0] * k0.x));
        float p01 = fast_exp2(fmaf(q0[3], k0.w, q0[2] * k0.z));
        float p02 = fast_exp2(fmaf(q0[5], k1.y, q0[4] * k1.x));
        float p03 = fast_exp2(fmaf(q0[7], k1.w, q0[6] * k1.z));
        float p10 = fast_exp2(fmaf(q1[1], k0.y, q1[0] * k0.x));
        float p11 = fast_exp2(fmaf(q1[3], k0.w, q1[2] * k0.z));
        float p12 = fast_exp2(fmaf(q1[5], k1.y, q1[4] * k1.x));
        float p13 = fast_exp2(fmaf(q1[7], k1.w, q1[6] * k1.z));
        l0[0] += p00; l0[1] += p01; l0[2] += p02; l0[3] += p03;
        l1[0] += p10; l1[1] += p11; l1[2] += p12; l1[3] += p13;
        S0[0] = fmaf(p00, uu.x, S0[0]); S0[1] = fmaf(p01, uu.y, S0[1]);
        S0[2] = fmaf(p02, uu.z, S0[2]); S0[3] = fmaf(p03, uu.w, S0[3]);
        S1[0] = fmaf(p10, uu.x, S1[0]); S1[1] = fmaf(p11, uu.y, S1[1]);
        S1[2] = fmaf(p12, uu.z, S1[2]); S1[3] = fmaf(p13, uu.w, S1[3]);
    }

    // combine the two s-halves (partner lane has same rows, other half)
#pragma unroll
    for (int i = 0; i < 4; ++i) {
        l0[i] += __shfl_xor(l0[i], 1);  S0[i] += __shfl_xor(S0[i], 1);
        l1[i] += __shfl_xor(l1[i], 1);  S1[i] += __shfl_xor(S1[i], 1);
    }

    float bsum = 0.0f;
#pragma unroll
    for (int fp = 0; fp < E_; ++fp) bsum += b_o[fp];
    float Sa = bsum, Sb = bsum;
#pragma unroll
    for (int hh = 0; hh < 4; ++hh) {
        Sa = fmaf(S0[hh], fast_rcp(l0[hh]), Sa);
        Sb = fmaf(S1[hh], fast_rcp(l1[hh]), Sb);
    }

    if (sh == 0) {
        tsf_imp[(size_t)b * T_ * C_ + (size_t)row0 * C_ + c] = fast_sigmoid(Sa);
        tsf_imp[(size_t)b * T_ * C_ + (size_t)row1 * C_ + c] = fast_sigmoid(Sb);
    }

    // feat: parity-safe butterfly (offsets 2..32) sums this wave's 64 rows
    float fsum = Sa + Sb;
#pragma unroll
    for (int off = 2; off <= 32; off <<= 1) fsum += __shfl_xor(fsum, off);
    if (lane == 0) red2[w] = fsum;
    __syncthreads();
    if (tid == 0) feat_imp[bc] = fast_sigmoid(red2[0] + red2[1]);
}

// ---------------------------------------------------------------------------
// K3: out0. grid = B, block = 64. (proven)
// ---------------------------------------------------------------------------
__global__ __launch_bounds__(64) void k_out(
    const float* __restrict__ fh, const float* __restrict__ W_out, const float* __restrict__ b_out,
    float* __restrict__ out0)
{
    const int b = blockIdx.x;
    const int tid = threadIdx.x;
    __shared__ float hf[C_ * E_];
    const float4* src = (const float4*)(fh + (b * C_ + tid) * E_);
    float4* dst = (float4*)(hf + tid * E_);
    dst[0] = src[0];
    dst[1] = src[1];
    __syncthreads();
    if (tid < HID_) {
        float a = b_out[tid];
        const float* wo = W_out + tid * (C_ * E_);
        for (int k = 0; k < C_ * E_; ++k) a = fmaf(hf[k], wo[k], a);
        out0[b * HID_ + tid] = a;
    }
}

// ---------------------------------------------------------------------------
extern "C" void kernel_launch(void* const* d_in, const int* in_sizes, int n_in,
                              void* d_out, int out_size, void* d_ws, size_t ws_size,
                              hipStream_t stream) {
    (void)in_sizes; (void)n_in; (void)out_size; (void)ws_size;

    float* out0 = (float*)d_out;                 // (B, HID)    1024
    float* feat = out0 + B_ * HID_;              // (B, C)      2048
    float* tsim = feat + B_ * C_;                // (B, T)      4096
    float* tsf  = tsim + B_ * T_;                // (B, T, C) 262144

    const float* x     = (const float*)d_in[0];
    const float* W_in  = (const float*)d_in[1];
    const float* b_in  = (const float*)d_in[2];
    const float* W_ts1 = (const float*)d_in[3];
    const float* b_ts1 = (const float*)d_in[4];
    const float* W_ts2 = (const float*)d_in[5];
    const float* b_ts2 = (const float*)d_in[6];
    const float* W_ih  = (const float*)d_in[7];
    const float* W_hh  = (const float*)d_in[8];
    const float* b_ih  = (const float*)d_in[9];
    const float* b_hh  = (const float*)d_in[10];
    const float* W_qkv = (const float*)d_in[11];
    const float* b_qkv = (const float*)d_in[12];
    const float* W_o   = (const float*)d_in[13];
    const float* b_o   = (const float*)d_in[14];
    const float* W_out = (const float*)d_in[15];
    const float* b_out = (const float*)d_in[16];

    // ws layout (f32): fh (64KB) | xp (1MB) | hs (8MB)
    float* fhb = (float*)d_ws;
    float* xpb = fhb + B_ * C_ * E_;
    float* hsb = xpb + (size_t)B_ * T_ * C_;

    hipLaunchKernelGGL(k_pre_ts, dim3(B_ * T_), dim3(64), 0, stream,
                       x, W_in, b_in, W_ts1, b_ts1, W_ts2, b_ts2, xpb, tsim);
    hipLaunchKernelGGL(k_gru, dim3(B_ * C_ / 8), dim3(64), 0, stream,
                       xpb, W_ih, W_hh, b_ih, b_hh, hsb, fhb);
    hipLaunchKernelGGL(k_out, dim3(B_), dim3(64), 0, stream,
                       fhb, W_out, b_out, out0);
    hipLaunchKernelGGL(k_attn, dim3(B_ * C_), dim3(128), 0, stream,
                       hsb, W_qkv, b_qkv, W_o, b_o, feat, tsf);
}